// Round 18
// baseline (84.136 us; speedup 1.0000x reference)
//
#include <hip/hip_runtime.h>
#include <math.h>

typedef unsigned short u16;
typedef unsigned int u32;
typedef unsigned long long u64;
typedef float    f32x4  __attribute__((ext_vector_type(4)));
typedef __bf16   bf16x8 __attribute__((ext_vector_type(8)));

#define NS    32768
#define KC    1024
#define INV_T 100.0f
#define TAU   1.25f

// ws layout (float offsets)
#define C2_OFF   0                          // 1024
#define X2_OFF   1024                       // 32768
#define SUMM_OFF (1024 + 32768)             // [n][32 blocks] float2 = 8 MB
#define SUMM_SZ  (NS * 32 * 2)
#define HIST_OFF (SUMM_OFF + SUMM_SZ)       // 1024
#define PD_OFF   (HIST_OFF + KC)            // 4096
#define PS_OFF   (PD_OFF + 4096)            // 4096

// ct: 32 tiles of 32 codes; chunk = ks*128 + sub*32 + row (8192 u16/tile, 512 KB)
#define CTILE_U16 8192

__device__ __forceinline__ void gload_lds16(const void* g, void* l) {
    __builtin_amdgcn_global_load_lds((const __attribute__((address_space(1))) void*)g,
                                     (__attribute__((address_space(3))) void*)l, 16, 0, 0);
}

// ---- prep: blocks 0..1023 compute x2 (32 samples each); blocks 1024..1087 do
//      codebook (c2 + ct tiles) + hist zeroing. ----
__global__ __launch_bounds__(256) void vq_prep(const float* __restrict__ x,
                                               const float* __restrict__ cb,
                                               u16* __restrict__ ct,
                                               float* __restrict__ x2,
                                               float* __restrict__ c2,
                                               float* __restrict__ hist) {
    const int t = threadIdx.x;
    if (blockIdx.x < 1024) {
        const int tl = blockIdx.x;            // 32-sample tile
        const float* src = x + (size_t)tl * 32 * 256;
        #pragma unroll
        for (int j = 0; j < 4; ++j) {
            int row = j * 8 + (t >> 5);       // 0..31
            int kq0 = (t & 31) * 2;           // float4 index, step 2
            float sq = 0.f;
            #pragma unroll
            for (int h = 0; h < 2; ++h) {
                float4 v = reinterpret_cast<const float4*>(src)[(size_t)row * 64 + kq0 + h];
                sq += v.x * v.x + v.y * v.y + v.z * v.z + v.w * v.w;
            }
            sq += __shfl_xor(sq, 1);  sq += __shfl_xor(sq, 2);
            sq += __shfl_xor(sq, 4);  sq += __shfl_xor(sq, 8);
            sq += __shfl_xor(sq, 16);
            if ((t & 31) == 0) x2[tl * 32 + row] = sq;
        }
    } else {
        const int b = blockIdx.x - 1024;      // 0..63
        const int w = t >> 6, lane = t & 63;

        if (t < 16) hist[b * 16 + t] = 0.f;

        #pragma unroll
        for (int i = 0; i < 4; ++i) {
            int g = b * 16 + i * 4 + w;
            float4 v = reinterpret_cast<const float4*>(cb)[(size_t)g * 64 + lane];
            float s = v.x * v.x + v.y * v.y + v.z * v.z + v.w * v.w;
            #pragma unroll
            for (int off = 32; off; off >>= 1) s += __shfl_xor(s, off);
            if (lane == 0) c2[g] = s;
        }

        const int T = b >> 1, p = b & 1;
        #pragma unroll
        for (int i = 0; i < 2; ++i) {
            int c = p * 512 + i * 256 + t;
            int ks = c >> 7, sub = (c >> 5) & 3, row = c & 31;
            const float* srcp = cb + (size_t)(T * 32 + row) * 256 + ks * 32 + sub * 8;
            float4 a0 = *reinterpret_cast<const float4*>(srcp);
            float4 a1 = *reinterpret_cast<const float4*>(srcp + 4);
            bf16x8 v;
            v[0]=(__bf16)a0.x; v[1]=(__bf16)a0.y; v[2]=(__bf16)a0.z; v[3]=(__bf16)a0.w;
            v[4]=(__bf16)a1.x; v[5]=(__bf16)a1.y; v[6]=(__bf16)a1.z; v[7]=(__bf16)a1.w;
            *reinterpret_cast<bf16x8*>(ct + (size_t)T * CTILE_U16 + (size_t)c * 8) = v;
        }
    }
}

// ---- distance MFMA: swapped operands (codes=rows, samples=cols).
//      A (32 samples/wave) loaded once from fp32 x and converted in-register;
//      B = 32-code tiles dbuf via LDS (2x16KB). grid 1024; 4 blocks/CU.
__global__ __launch_bounds__(256, 4) void vq_dist(const float* __restrict__ x,
                                                  const u16* __restrict__ ct,
                                                  const float* __restrict__ c2,
                                                  float2* __restrict__ summ) {
    __shared__ __align__(16) u16 Bs[2][CTILE_U16];   // 2 x 16 KB

    const int id = blockIdx.x;
    const int xcd = id & 7, j = id >> 3;
    const int sq = xcd * 32 + (j >> 2);
    const int q  = j & 3;
    const int sBase = sq * 128;

    const int t = threadIdx.x, w = t >> 6, lane = t & 63;
    const int lo16 = lane & 15, hi = lane >> 4;
    const int hi4 = hi * 4;

    #define STAGE(buf, bt)                                                        \
        do {                                                                      \
            const u16* bT_ = ct + (size_t)(bt) * CTILE_U16;                       \
            _Pragma("unroll")                                                     \
            for (int i_ = 0; i_ < 4; ++i_) {                                      \
                int c0_ = (i_ * 4 + w) * 64;                                      \
                gload_lds16(bT_ + (size_t)(c0_ + lane) * 8, &Bs[buf][c0_ * 8]);   \
            }                                                                     \
        } while (0)

    STAGE(0, q * 8);

    // A-operand: 32 samples x 256 k, loaded from fp32 x, converted to bf16 (64 regs)
    const float* aw = x + (size_t)(sBase + w * 32) * 256;
    bf16x8 af[2][8];
    #pragma unroll
    for (int sm = 0; sm < 2; ++sm) {
        #pragma unroll
        for (int ks = 0; ks < 8; ++ks) {
            const float* ap = aw + (size_t)(sm * 16 + lo16) * 256 + ks * 32 + hi * 8;
            float4 a0 = *reinterpret_cast<const float4*>(ap);
            float4 a1 = *reinterpret_cast<const float4*>(ap + 4);
            bf16x8 v;
            v[0]=(__bf16)a0.x; v[1]=(__bf16)a0.y; v[2]=(__bf16)a0.z; v[3]=(__bf16)a0.w;
            v[4]=(__bf16)a1.x; v[5]=(__bf16)a1.y; v[6]=(__bf16)a1.z; v[7]=(__bf16)a1.w;
            af[sm][ks] = v;
        }
    }
    __syncthreads();

    int cur = 0;
    for (int tt = 0; tt < 8; ++tt) {
        if (tt < 7) STAGE(cur ^ 1, q * 8 + tt + 1);

        f32x4 acc[2][2];
        #pragma unroll
        for (int cn = 0; cn < 2; ++cn)
            #pragma unroll
            for (int sm = 0; sm < 2; ++sm) acc[cn][sm] = (f32x4)0.f;

        const u16* bsc = &Bs[cur][0];
        #pragma unroll
        for (int ks = 0; ks < 8; ++ks) {
            bf16x8 bfr[2];
            #pragma unroll
            for (int cn = 0; cn < 2; ++cn)
                bfr[cn] = *reinterpret_cast<const bf16x8*>(
                    &bsc[((size_t)ks * 128 + hi * 32 + cn * 16 + lo16) * 8]);
            #pragma unroll
            for (int cn = 0; cn < 2; ++cn)
                #pragma unroll
                for (int sm = 0; sm < 2; ++sm)
                    acc[cn][sm] = __builtin_amdgcn_mfma_f32_16x16x32_bf16(
                        bfr[cn], af[sm][ks], acc[cn][sm], 0, 0, 0);
        }

        const int cBase = q * 256 + tt * 32;
        float c2v[2][4];
        #pragma unroll
        for (int cn = 0; cn < 2; ++cn)
            #pragma unroll
            for (int r = 0; r < 4; ++r)
                c2v[cn][r] = c2[cBase + cn * 16 + hi4 + r];

        #pragma unroll
        for (int sm = 0; sm < 2; ++sm) {
            float dd[2][4];
            #pragma unroll
            for (int cn = 0; cn < 2; ++cn)
                #pragma unroll
                for (int r = 0; r < 4; ++r)
                    dd[cn][r] = fmaf(-2.0f, acc[cn][sm][r], c2v[cn][r]);
            float bm = dd[0][0];
            #pragma unroll
            for (int cn = 0; cn < 2; ++cn)
                #pragma unroll
                for (int r = 0; r < 4; ++r) bm = fminf(bm, dd[cn][r]);
            bm = fminf(bm, __shfl_xor(bm, 16));
            bm = fminf(bm, __shfl_xor(bm, 32));
            const float thr = bm + TAU;
            u32 m32 = 0;
            #pragma unroll
            for (int cn = 0; cn < 2; ++cn)
                #pragma unroll
                for (int r = 0; r < 4; ++r)
                    m32 |= (dd[cn][r] < thr ? 1u : 0u) << (cn * 16 + hi4 + r);
            m32 |= __shfl_xor(m32, 16);
            m32 |= __shfl_xor(m32, 32);
            if (hi == 0) {
                const int R = sBase + w * 32 + sm * 16 + lo16;
                float2 o; o.x = bm; o.y = __uint_as_float(m32);
                summ[(size_t)R * 32 + q * 8 + tt] = o;
            }
        }
        __syncthreads();
        cur ^= 1;
    }
    #undef STAGE
}

// ---- exact fp32 refine: 2 samples/wave (32-lane halves), ballot-driven ----
__global__ __launch_bounds__(256) void vq_refine(const float* __restrict__ x,
                                                 const float* __restrict__ cb,
                                                 const float* __restrict__ c2,
                                                 const float* __restrict__ x2,
                                                 const float2* __restrict__ summ,
                                                 float* __restrict__ hist,
                                                 float* __restrict__ pd,
                                                 float* __restrict__ ps,
                                                 float* __restrict__ outq,
                                                 float* __restrict__ out_idx_f) {
    __shared__ int   cd_k[4][2][64];
    __shared__ float cd_d[4][2][64];
    __shared__ float rd[8], rs[8];

    const int wid = threadIdx.x >> 6, lane = threadIdx.x & 63;
    const int half = lane >> 5, l32 = lane & 31;
    const int s = blockIdx.x * 8 + wid * 2 + half;

    const float4* x4  = reinterpret_cast<const float4*>(x);
    const float4* cb4 = reinterpret_cast<const float4*>(cb);

    const float4 xr0 = x4[(size_t)s * 64 + l32];
    const float4 xr1 = x4[(size_t)s * 64 + 32 + l32];
    const float x2s = x2[s];

    const float2 smv = summ[(size_t)s * 32 + l32];
    float gm = smv.x;
    gm = fminf(gm, __shfl_xor(gm, 1));  gm = fminf(gm, __shfl_xor(gm, 2));
    gm = fminf(gm, __shfl_xor(gm, 4));  gm = fminf(gm, __shfl_xor(gm, 8));
    gm = fminf(gm, __shfl_xor(gm, 16));
    const float lim = gm + TAU;

    u64 ball = __ballot(smv.x <= lim);
    u32 act = (u32)(ball >> (half * 32));

    float m = 3.4e38f, S1 = 0.f, S2 = 0.f;
    int bk = 0, cnt = 0;

    while (act) {
        const int hb = __ffs(act) - 1; act &= act - 1;
        u32 mk = __float_as_uint(__shfl(smv.y, half * 32 + hb));
        while (mk) {
            int vc = 1;
            int b0 = __ffs(mk) - 1; mk &= mk - 1;
            int k0 = hb * 32 + b0, k1 = k0, k2 = k0, k3 = k0;
            if (mk) { int b = __ffs(mk) - 1; mk &= mk - 1; k1 = hb * 32 + b; vc = 2; }
            if (mk) { int b = __ffs(mk) - 1; mk &= mk - 1; k2 = hb * 32 + b; vc = 3; }
            if (mk) { int b = __ffs(mk) - 1; mk &= mk - 1; k3 = hb * 32 + b; vc = 4; }

            float4 a0 = cb4[(size_t)k0 * 64 + l32], b0v = cb4[(size_t)k0 * 64 + 32 + l32];
            float4 a1 = cb4[(size_t)k1 * 64 + l32], b1v = cb4[(size_t)k1 * 64 + 32 + l32];
            float4 a2 = cb4[(size_t)k2 * 64 + l32], b2v = cb4[(size_t)k2 * 64 + 32 + l32];
            float4 a3 = cb4[(size_t)k3 * 64 + l32], b3v = cb4[(size_t)k3 * 64 + 32 + l32];
            float r0 = xr0.x*a0.x + xr0.y*a0.y + xr0.z*a0.z + xr0.w*a0.w
                     + xr1.x*b0v.x + xr1.y*b0v.y + xr1.z*b0v.z + xr1.w*b0v.w;
            float r1 = xr0.x*a1.x + xr0.y*a1.y + xr0.z*a1.z + xr0.w*a1.w
                     + xr1.x*b1v.x + xr1.y*b1v.y + xr1.z*b1v.z + xr1.w*b1v.w;
            float r2 = xr0.x*a2.x + xr0.y*a2.y + xr0.z*a2.z + xr0.w*a2.w
                     + xr1.x*b2v.x + xr1.y*b2v.y + xr1.z*b2v.z + xr1.w*b2v.w;
            float r3 = xr0.x*a3.x + xr0.y*a3.y + xr0.z*a3.z + xr0.w*a3.w
                     + xr1.x*b3v.x + xr1.y*b3v.y + xr1.z*b3v.z + xr1.w*b3v.w;
            #pragma unroll
            for (int off = 1; off < 32; off <<= 1) {
                r0 += __shfl_xor(r0, off);
                r1 += __shfl_xor(r1, off);
                r2 += __shfl_xor(r2, off);
                r3 += __shfl_xor(r3, off);
            }
            float dk[4];
            dk[0] = (x2s - 2.0f * r0) + c2[k0];
            dk[1] = (x2s - 2.0f * r1) + c2[k1];
            dk[2] = (x2s - 2.0f * r2) + c2[k2];
            dk[3] = (x2s - 2.0f * r3) + c2[k3];
            int kk[4] = {k0, k1, k2, k3};

            #pragma unroll
            for (int jj = 0; jj < 4; ++jj) {
                if (jj >= vc) break;
                float d = dk[jj];
                if (l32 == 0 && cnt < 64) { cd_k[wid][half][cnt] = kk[jj]; cd_d[wid][half][cnt] = d; }
                ++cnt;
                if (S1 == 0.f)   { m = d; S1 = 1.f; S2 = 0.f; bk = kk[jj]; }
                else if (d < m)  { float f = __expf((d - m) * INV_T);
                                   S2 = f * (S2 + (m - d) * S1);
                                   S1 = S1 * f + 1.f; m = d; bk = kk[jj]; }
                else             { float e = __expf((m - d) * INV_T);
                                   S1 += e; S2 += e * (d - m); }
            }
        }
    }
    float sent = S2 * INV_T / S1 + logf(S1);
    if (l32 == 0) { rd[wid * 2 + half] = m; rs[wid * 2 + half] = sent; }

    if (cnt > 64) cnt = 64;
    for (int c = l32; c < cnt; c += 32) {
        float dkv = cd_d[wid][half][c]; int k = cd_k[wid][half][c];
        atomicAdd(&hist[k], __expf((m - dkv) * INV_T) / S1);
    }

    reinterpret_cast<float4*>(outq)[(size_t)s * 64 + l32]      = cb4[(size_t)bk * 64 + l32];
    reinterpret_cast<float4*>(outq)[(size_t)s * 64 + 32 + l32] = cb4[(size_t)bk * 64 + 32 + l32];
    if (l32 == 0) out_idx_f[s] = (float)bk;

    __syncthreads();
    if (threadIdx.x == 0) {
        float sd = 0.f, se = 0.f;
        #pragma unroll
        for (int i = 0; i < 8; ++i) { sd += rd[i]; se += rs[i]; }
        pd[blockIdx.x] = sd;
        ps[blockIdx.x] = se;
    }
}

// -------------------------------------------------------------- finalize ----
__global__ __launch_bounds__(256) void vq_finalize(const float* __restrict__ hist,
                                                   const float* __restrict__ pd,
                                                   const float* __restrict__ ps,
                                                   float* __restrict__ loss_out) {
    float ae = 0.f, sd = 0.f, se = 0.f;
    for (int k = threadIdx.x; k < KC; k += 256) {
        float p = hist[k] * (1.0f / (float)NS);
        ae += -p * logf(p + 1e-5f);
    }
    for (int b = threadIdx.x; b < 4096; b += 256) { sd += pd[b]; se += ps[b]; }
    #pragma unroll
    for (int off = 32; off; off >>= 1) {
        ae += __shfl_xor(ae, off); sd += __shfl_xor(sd, off); se += __shfl_xor(se, off);
    }
    __shared__ float r[3][4];
    int wid = threadIdx.x >> 6, lane = threadIdx.x & 63;
    if (lane == 0) { r[0][wid] = ae; r[1][wid] = sd; r[2][wid] = se; }
    __syncthreads();
    if (threadIdx.x == 0) {
        float AE = r[0][0] + r[0][1] + r[0][2] + r[0][3];
        float SD = r[1][0] + r[1][1] + r[1][2] + r[1][3];
        float SE = r[2][0] + r[2][1] + r[2][2] + r[2][3];
        float latent = 1.25f * SD / 8388608.0f;
        loss_out[0] = latent + 0.1f * (SE * (1.0f / (float)NS) - AE);
    }
}

extern "C" void kernel_launch(void* const* d_in, const int* in_sizes, int n_in,
                              void* d_out, int out_size, void* d_ws, size_t ws_size,
                              hipStream_t stream) {
    const float* x  = (const float*)d_in[0];
    const float* cb = (const float*)d_in[1];
    float* out = (float*)d_out;
    float* ws  = (float*)d_ws;

    // bf16 codebook tiles in d_out's quantized region (overwritten by refine later)
    u16* ct = (u16*)d_out;                       // 512 KB

    vq_prep<<<1088, 256, 0, stream>>>(x, cb, ct,
                                      ws + X2_OFF, ws + C2_OFF, ws + HIST_OFF);
    vq_dist<<<1024, 256, 0, stream>>>(x, ct, ws + C2_OFF, (float2*)(ws + SUMM_OFF));
    vq_refine<<<NS / 8, 256, 0, stream>>>(x, cb, ws + C2_OFF, ws + X2_OFF,
                                          (const float2*)(ws + SUMM_OFF),
                                          ws + HIST_OFF, ws + PD_OFF, ws + PS_OFF,
                                          out, out + 8388609);
    vq_finalize<<<1, 256, 0, stream>>>(ws + HIST_OFF, ws + PD_OFF, ws + PS_OFF,
                                       out + 8388608);
}

// Round 19
// 77.818 us; speedup vs baseline: 1.0812x; 1.0812x over previous
//
#include <hip/hip_runtime.h>
#include <math.h>

typedef unsigned short u16;
typedef unsigned int u32;
typedef unsigned long long u64;
typedef float    f32x4  __attribute__((ext_vector_type(4)));
typedef __bf16   bf16x8 __attribute__((ext_vector_type(8)));

#define NS    32768
#define KC    1024
#define INV_T 100.0f
#define TAU   1.25f

// ws layout (float offsets)
#define C2_OFF   0                          // 1024
#define X2_OFF   1024                       // 32768
#define SUMM_OFF (1024 + 32768)             // [n][32 blocks] float2 = 8 MB
#define SUMM_SZ  (NS * 32 * 2)
#define HIST_OFF (SUMM_OFF + SUMM_SZ)       // 1024
#define PD_OFF   (HIST_OFF + KC)            // 4096
#define PS_OFF   (PD_OFF + 4096)            // 4096

// Fragment-chunk layouts (16B chunks of 8 bf16):
//  xb: 1024 tiles of 32 samples; chunk = ks*128 + sub*32 + row   (8192 u16/tile)
//  ct: 32 tiles of 32 codes;     chunk = ks*128 + sub*32 + row   (8192 u16/tile)
#define XTILE_U16 8192
#define CTILE_U16 8192

__device__ __forceinline__ u16 f2bf(float f) {
    unsigned u = __float_as_uint(f);
    return (u16)((u + 0x7FFFu + ((u >> 16) & 1u)) >> 16);
}

__device__ __forceinline__ void gload_lds16(const void* g, void* l) {
    __builtin_amdgcn_global_load_lds((const __attribute__((address_space(1))) void*)g,
                                     (__attribute__((address_space(3))) void*)l, 16, 0, 0);
}

// ---- prep: blocks 0..1023 convert x -> xb tiles + x2; blocks 1024..1087 do
//      codebook (c2 + ct tiles) + hist zeroing. One kernel, one gap. ----
__global__ __launch_bounds__(256) void vq_prep(const float* __restrict__ x,
                                               const float* __restrict__ cb,
                                               u16* __restrict__ xb,
                                               u16* __restrict__ ct,
                                               float* __restrict__ x2,
                                               float* __restrict__ c2,
                                               float* __restrict__ hist) {
    const int t = threadIdx.x;
    if (blockIdx.x < 1024) {
        const int tl = blockIdx.x;            // 32-sample tile
        const float* src = x + (size_t)tl * 32 * 256;
        u16* dst = xb + (size_t)tl * XTILE_U16;
        #pragma unroll
        for (int j = 0; j < 4; ++j) {
            int row = j * 8 + (t >> 5);       // 0..31
            int kq0 = (t & 31) * 2;           // float4 index, step 2
            float sq = 0.f;
            #pragma unroll
            for (int h = 0; h < 2; ++h) {
                int kq = kq0 + h;             // 0..63
                float4 v = reinterpret_cast<const float4*>(src)[(size_t)row * 64 + kq];
                sq += v.x * v.x + v.y * v.y + v.z * v.z + v.w * v.w;
                int kk = kq * 4;
                int kss = kk >> 5, sub = (kk >> 3) & 3, half = kq & 1;
                ushort4 o;
                o.x = f2bf(v.x); o.y = f2bf(v.y); o.z = f2bf(v.z); o.w = f2bf(v.w);
                *reinterpret_cast<ushort4*>(
                    dst + ((size_t)kss * 128 + sub * 32 + row) * 8 + half * 4) = o;
            }
            sq += __shfl_xor(sq, 1);  sq += __shfl_xor(sq, 2);
            sq += __shfl_xor(sq, 4);  sq += __shfl_xor(sq, 8);
            sq += __shfl_xor(sq, 16);
            if ((t & 31) == 0) x2[tl * 32 + row] = sq;
        }
    } else {
        const int b = blockIdx.x - 1024;      // 0..63
        const int w = t >> 6, lane = t & 63;

        if (t < 16) hist[b * 16 + t] = 0.f;

        #pragma unroll
        for (int i = 0; i < 4; ++i) {
            int g = b * 16 + i * 4 + w;
            float4 v = reinterpret_cast<const float4*>(cb)[(size_t)g * 64 + lane];
            float s = v.x * v.x + v.y * v.y + v.z * v.z + v.w * v.w;
            #pragma unroll
            for (int off = 32; off; off >>= 1) s += __shfl_xor(s, off);
            if (lane == 0) c2[g] = s;
        }

        const int T = b >> 1, p = b & 1;
        #pragma unroll
        for (int i = 0; i < 2; ++i) {
            int c = p * 512 + i * 256 + t;
            int ks = c >> 7, sub = (c >> 5) & 3, row = c & 31;
            const float* srcp = cb + (size_t)(T * 32 + row) * 256 + ks * 32 + sub * 8;
            float4 a0 = *reinterpret_cast<const float4*>(srcp);
            float4 a1 = *reinterpret_cast<const float4*>(srcp + 4);
            bf16x8 v;
            v[0]=(__bf16)a0.x; v[1]=(__bf16)a0.y; v[2]=(__bf16)a0.z; v[3]=(__bf16)a0.w;
            v[4]=(__bf16)a1.x; v[5]=(__bf16)a1.y; v[6]=(__bf16)a1.z; v[7]=(__bf16)a1.w;
            *reinterpret_cast<bf16x8*>(ct + (size_t)T * CTILE_U16 + (size_t)c * 8) = v;
        }
    }
}

// ---- distance MFMA: swapped operands (codes=rows, samples=cols).
//      A (32 samples/wave) persistent in regs; B = 32-code tiles dbuf via LDS
//      (2x16KB). grid 1024 = 256 sample-groups x 4 quarters; 4 blocks/CU.
__global__ __launch_bounds__(256, 4) void vq_dist(const u16* __restrict__ xb,
                                                  const u16* __restrict__ ct,
                                                  const float* __restrict__ c2,
                                                  float2* __restrict__ summ) {
    __shared__ __align__(16) u16 Bs[2][CTILE_U16];   // 2 x 16 KB

    const int id = blockIdx.x;
    const int xcd = id & 7, j = id >> 3;
    const int sq = xcd * 32 + (j >> 2);
    const int q  = j & 3;
    const int sBase = sq * 128;

    const int t = threadIdx.x, w = t >> 6, lane = t & 63;
    const int lo16 = lane & 15, hi = lane >> 4;
    const int hi4 = hi * 4;

    #define STAGE(buf, bt)                                                        \
        do {                                                                      \
            const u16* bT_ = ct + (size_t)(bt) * CTILE_U16;                       \
            _Pragma("unroll")                                                     \
            for (int i_ = 0; i_ < 4; ++i_) {                                      \
                int c0_ = (i_ * 4 + w) * 64;                                      \
                gload_lds16(bT_ + (size_t)(c0_ + lane) * 8, &Bs[buf][c0_ * 8]);   \
            }                                                                     \
        } while (0)

    STAGE(0, q * 8);

    const u16* aT = xb + (size_t)(sq * 4 + w) * XTILE_U16;
    bf16x8 af[2][8];
    #pragma unroll
    for (int sm = 0; sm < 2; ++sm)
        #pragma unroll
        for (int ks = 0; ks < 8; ++ks)
            af[sm][ks] = *reinterpret_cast<const bf16x8*>(
                aT + ((size_t)ks * 128 + hi * 32 + sm * 16 + lo16) * 8);
    __syncthreads();

    int cur = 0;
    for (int tt = 0; tt < 8; ++tt) {
        if (tt < 7) STAGE(cur ^ 1, q * 8 + tt + 1);

        f32x4 acc[2][2];
        #pragma unroll
        for (int cn = 0; cn < 2; ++cn)
            #pragma unroll
            for (int sm = 0; sm < 2; ++sm) acc[cn][sm] = (f32x4)0.f;

        const u16* bsc = &Bs[cur][0];
        #pragma unroll
        for (int ks = 0; ks < 8; ++ks) {
            bf16x8 bfr[2];
            #pragma unroll
            for (int cn = 0; cn < 2; ++cn)
                bfr[cn] = *reinterpret_cast<const bf16x8*>(
                    &bsc[((size_t)ks * 128 + hi * 32 + cn * 16 + lo16) * 8]);
            #pragma unroll
            for (int cn = 0; cn < 2; ++cn)
                #pragma unroll
                for (int sm = 0; sm < 2; ++sm)
                    acc[cn][sm] = __builtin_amdgcn_mfma_f32_16x16x32_bf16(
                        bfr[cn], af[sm][ks], acc[cn][sm], 0, 0, 0);
        }

        const int cBase = q * 256 + tt * 32;
        float c2v[2][4];
        #pragma unroll
        for (int cn = 0; cn < 2; ++cn)
            #pragma unroll
            for (int r = 0; r < 4; ++r)
                c2v[cn][r] = c2[cBase + cn * 16 + hi4 + r];

        #pragma unroll
        for (int sm = 0; sm < 2; ++sm) {
            float dd[2][4];
            #pragma unroll
            for (int cn = 0; cn < 2; ++cn)
                #pragma unroll
                for (int r = 0; r < 4; ++r)
                    dd[cn][r] = fmaf(-2.0f, acc[cn][sm][r], c2v[cn][r]);
            float bm = dd[0][0];
            #pragma unroll
            for (int cn = 0; cn < 2; ++cn)
                #pragma unroll
                for (int r = 0; r < 4; ++r) bm = fminf(bm, dd[cn][r]);
            bm = fminf(bm, __shfl_xor(bm, 16));
            bm = fminf(bm, __shfl_xor(bm, 32));
            const float thr = bm + TAU;
            u32 m32 = 0;
            #pragma unroll
            for (int cn = 0; cn < 2; ++cn)
                #pragma unroll
                for (int r = 0; r < 4; ++r)
                    m32 |= (dd[cn][r] < thr ? 1u : 0u) << (cn * 16 + hi4 + r);
            m32 |= __shfl_xor(m32, 16);
            m32 |= __shfl_xor(m32, 32);
            if (hi == 0) {
                const int R = sBase + w * 32 + sm * 16 + lo16;
                float2 o; o.x = bm; o.y = __uint_as_float(m32);
                summ[(size_t)R * 32 + q * 8 + tt] = o;
            }
        }
        __syncthreads();
        cur ^= 1;
    }
    #undef STAGE
}

// ---- exact fp32 refine: 2 samples/wave (32-lane halves), ballot-driven ----
__global__ __launch_bounds__(256) void vq_refine(const float* __restrict__ x,
                                                 const float* __restrict__ cb,
                                                 const float* __restrict__ c2,
                                                 const float* __restrict__ x2,
                                                 const float2* __restrict__ summ,
                                                 float* __restrict__ hist,
                                                 float* __restrict__ pd,
                                                 float* __restrict__ ps,
                                                 float* __restrict__ outq,
                                                 float* __restrict__ out_idx_f) {
    __shared__ int   cd_k[4][2][64];
    __shared__ float cd_d[4][2][64];
    __shared__ float rd[8], rs[8];

    const int wid = threadIdx.x >> 6, lane = threadIdx.x & 63;
    const int half = lane >> 5, l32 = lane & 31;
    const int s = blockIdx.x * 8 + wid * 2 + half;

    const float4* x4  = reinterpret_cast<const float4*>(x);
    const float4* cb4 = reinterpret_cast<const float4*>(cb);

    const float4 xr0 = x4[(size_t)s * 64 + l32];
    const float4 xr1 = x4[(size_t)s * 64 + 32 + l32];
    const float x2s = x2[s];

    const float2 smv = summ[(size_t)s * 32 + l32];
    float gm = smv.x;
    gm = fminf(gm, __shfl_xor(gm, 1));  gm = fminf(gm, __shfl_xor(gm, 2));
    gm = fminf(gm, __shfl_xor(gm, 4));  gm = fminf(gm, __shfl_xor(gm, 8));
    gm = fminf(gm, __shfl_xor(gm, 16));
    const float lim = gm + TAU;

    u64 ball = __ballot(smv.x <= lim);
    u32 act = (u32)(ball >> (half * 32));

    float m = 3.4e38f, S1 = 0.f, S2 = 0.f;
    int bk = 0, cnt = 0;

    while (act) {
        const int hb = __ffs(act) - 1; act &= act - 1;
        u32 mk = __float_as_uint(__shfl(smv.y, half * 32 + hb));
        while (mk) {
            int vc = 1;
            int b0 = __ffs(mk) - 1; mk &= mk - 1;
            int k0 = hb * 32 + b0, k1 = k0, k2 = k0, k3 = k0;
            if (mk) { int b = __ffs(mk) - 1; mk &= mk - 1; k1 = hb * 32 + b; vc = 2; }
            if (mk) { int b = __ffs(mk) - 1; mk &= mk - 1; k2 = hb * 32 + b; vc = 3; }
            if (mk) { int b = __ffs(mk) - 1; mk &= mk - 1; k3 = hb * 32 + b; vc = 4; }

            float4 a0 = cb4[(size_t)k0 * 64 + l32], b0v = cb4[(size_t)k0 * 64 + 32 + l32];
            float4 a1 = cb4[(size_t)k1 * 64 + l32], b1v = cb4[(size_t)k1 * 64 + 32 + l32];
            float4 a2 = cb4[(size_t)k2 * 64 + l32], b2v = cb4[(size_t)k2 * 64 + 32 + l32];
            float4 a3 = cb4[(size_t)k3 * 64 + l32], b3v = cb4[(size_t)k3 * 64 + 32 + l32];
            float r0 = xr0.x*a0.x + xr0.y*a0.y + xr0.z*a0.z + xr0.w*a0.w
                     + xr1.x*b0v.x + xr1.y*b0v.y + xr1.z*b0v.z + xr1.w*b0v.w;
            float r1 = xr0.x*a1.x + xr0.y*a1.y + xr0.z*a1.z + xr0.w*a1.w
                     + xr1.x*b1v.x + xr1.y*b1v.y + xr1.z*b1v.z + xr1.w*b1v.w;
            float r2 = xr0.x*a2.x + xr0.y*a2.y + xr0.z*a2.z + xr0.w*a2.w
                     + xr1.x*b2v.x + xr1.y*b2v.y + xr1.z*b2v.z + xr1.w*b2v.w;
            float r3 = xr0.x*a3.x + xr0.y*a3.y + xr0.z*a3.z + xr0.w*a3.w
                     + xr1.x*b3v.x + xr1.y*b3v.y + xr1.z*b3v.z + xr1.w*b3v.w;
            #pragma unroll
            for (int off = 1; off < 32; off <<= 1) {
                r0 += __shfl_xor(r0, off);
                r1 += __shfl_xor(r1, off);
                r2 += __shfl_xor(r2, off);
                r3 += __shfl_xor(r3, off);
            }
            float dk[4];
            dk[0] = (x2s - 2.0f * r0) + c2[k0];
            dk[1] = (x2s - 2.0f * r1) + c2[k1];
            dk[2] = (x2s - 2.0f * r2) + c2[k2];
            dk[3] = (x2s - 2.0f * r3) + c2[k3];
            int kk[4] = {k0, k1, k2, k3};

            #pragma unroll
            for (int jj = 0; jj < 4; ++jj) {
                if (jj >= vc) break;
                float d = dk[jj];
                if (l32 == 0 && cnt < 64) { cd_k[wid][half][cnt] = kk[jj]; cd_d[wid][half][cnt] = d; }
                ++cnt;
                if (S1 == 0.f)   { m = d; S1 = 1.f; S2 = 0.f; bk = kk[jj]; }
                else if (d < m)  { float f = __expf((d - m) * INV_T);
                                   S2 = f * (S2 + (m - d) * S1);
                                   S1 = S1 * f + 1.f; m = d; bk = kk[jj]; }
                else             { float e = __expf((m - d) * INV_T);
                                   S1 += e; S2 += e * (d - m); }
            }
        }
    }
    float sent = S2 * INV_T / S1 + logf(S1);
    if (l32 == 0) { rd[wid * 2 + half] = m; rs[wid * 2 + half] = sent; }

    if (cnt > 64) cnt = 64;
    for (int c = l32; c < cnt; c += 32) {
        float dkv = cd_d[wid][half][c]; int k = cd_k[wid][half][c];
        atomicAdd(&hist[k], __expf((m - dkv) * INV_T) / S1);
    }

    reinterpret_cast<float4*>(outq)[(size_t)s * 64 + l32]      = cb4[(size_t)bk * 64 + l32];
    reinterpret_cast<float4*>(outq)[(size_t)s * 64 + 32 + l32] = cb4[(size_t)bk * 64 + 32 + l32];
    if (l32 == 0) out_idx_f[s] = (float)bk;

    __syncthreads();
    if (threadIdx.x == 0) {
        float sd = 0.f, se = 0.f;
        #pragma unroll
        for (int i = 0; i < 8; ++i) { sd += rd[i]; se += rs[i]; }
        pd[blockIdx.x] = sd;
        ps[blockIdx.x] = se;
    }
}

// -------------------------------------------------------------- finalize ----
__global__ __launch_bounds__(256) void vq_finalize(const float* __restrict__ hist,
                                                   const float* __restrict__ pd,
                                                   const float* __restrict__ ps,
                                                   float* __restrict__ loss_out) {
    float ae = 0.f, sd = 0.f, se = 0.f;
    for (int k = threadIdx.x; k < KC; k += 256) {
        float p = hist[k] * (1.0f / (float)NS);
        ae += -p * logf(p + 1e-5f);
    }
    for (int b = threadIdx.x; b < 4096; b += 256) { sd += pd[b]; se += ps[b]; }
    #pragma unroll
    for (int off = 32; off; off >>= 1) {
        ae += __shfl_xor(ae, off); sd += __shfl_xor(sd, off); se += __shfl_xor(se, off);
    }
    __shared__ float r[3][4];
    int wid = threadIdx.x >> 6, lane = threadIdx.x & 63;
    if (lane == 0) { r[0][wid] = ae; r[1][wid] = sd; r[2][wid] = se; }
    __syncthreads();
    if (threadIdx.x == 0) {
        float AE = r[0][0] + r[0][1] + r[0][2] + r[0][3];
        float SD = r[1][0] + r[1][1] + r[1][2] + r[1][3];
        float SE = r[2][0] + r[2][1] + r[2][2] + r[2][3];
        float latent = 1.25f * SD / 8388608.0f;
        loss_out[0] = latent + 0.1f * (SE * (1.0f / (float)NS) - AE);
    }
}

extern "C" void kernel_launch(void* const* d_in, const int* in_sizes, int n_in,
                              void* d_out, int out_size, void* d_ws, size_t ws_size,
                              hipStream_t stream) {
    const float* x  = (const float*)d_in[0];
    const float* cb = (const float*)d_in[1];
    float* out = (float*)d_out;
    float* ws  = (float*)d_ws;

    // bf16 scratch in d_out's quantized region (overwritten by refine later):
    u16* xb = (u16*)d_out;                       // 16 MB
    u16* ct = (u16*)(out + 4194304);             // 512 KB

    vq_prep<<<1088, 256, 0, stream>>>(x, cb, xb, ct,
                                      ws + X2_OFF, ws + C2_OFF, ws + HIST_OFF);
    vq_dist<<<1024, 256, 0, stream>>>(xb, ct, ws + C2_OFF, (float2*)(ws + SUMM_OFF));
    vq_refine<<<NS / 8, 256, 0, stream>>>(x, cb, ws + C2_OFF, ws + X2_OFF,
                                          (const float2*)(ws + SUMM_OFF),
                                          ws + HIST_OFF, ws + PD_OFF, ws + PS_OFF,
                                          out, out + 8388609);
    vq_finalize<<<1, 256, 0, stream>>>(ws + HIST_OFF, ws + PD_OFF, ws + PS_OFF,
                                       out + 8388608);
}